// Round 1
// 114.005 us; speedup vs baseline: 1.0160x; 1.0160x over previous
//
#include <hip/hip_runtime.h>

#define BATCH 512
#define SEQ   512
#define VOCAB 1000
#define EMB   100
#define UNITS 64

typedef float v2f __attribute__((ext_vector_type(2)));

// ---------------------------------------------------------------------------
// Kernel 1: P[v][u] = 2*(sum_d emb[v][d] * Wxh[d][u] + b[u])   (VOCAB x UNITS)
// x2 pre-scale is an exact power-of-2 (commutes with fp rounding): the scan
// then feeds y directly into exp(y) for tanh(s)=1-2/(exp(2s)+1), saving a
// dependent v_mul per step.
// ---------------------------------------------------------------------------
__global__ __launch_bounds__(64) void proj_kernel(
    const float* __restrict__ emb, const float* __restrict__ Wxh,
    const float* __restrict__ bias, float* __restrict__ P) {
  const int v = blockIdx.x;
  const int u = threadIdx.x;
  const float* e = emb + v * EMB;
  float acc = bias[u];
#pragma unroll 5
  for (int d = 0; d < EMB; ++d) acc += e[d] * Wxh[d * UNITS + u];
  P[v * UNITS + u] = 2.f * acc;
}

// ---------------------------------------------------------------------------
// DPP all-gather of one value/lane across the lane's own 16-lane row.
// Structure guarantees completeness (4 quad_perm broadcasts cover the quad,
// row_ror 4/8/12 cover the other 3 quads) for EITHER rotate direction; the
// exact slot->source-lane permutation is discovered at runtime by running
// the same gather on lane_id (calibration) and permuting the weights.
// ---------------------------------------------------------------------------
#define DPP_I(src, ctrl) __builtin_amdgcn_update_dpp(0, (src), (ctrl), 0xF, 0xF, true)

#define GATHER_ROW(v_, g_)                                          \
  do {                                                              \
    g_[0] = DPP_I((v_), 0x00);  /* quad_perm:[0,0,0,0] */           \
    g_[1] = DPP_I((v_), 0x55);  /* quad_perm:[1,1,1,1] */           \
    g_[2] = DPP_I((v_), 0xAA);  /* quad_perm:[2,2,2,2] */           \
    g_[3] = DPP_I((v_), 0xFF);  /* quad_perm:[3,3,3,3] */           \
    g_[4]  = DPP_I(g_[0], 0x124); g_[5]  = DPP_I(g_[1], 0x124);     \
    g_[6]  = DPP_I(g_[2], 0x124); g_[7]  = DPP_I(g_[3], 0x124);     \
    g_[8]  = DPP_I(g_[0], 0x128); g_[9]  = DPP_I(g_[1], 0x128);     \
    g_[10] = DPP_I(g_[2], 0x128); g_[11] = DPP_I(g_[3], 0x128);     \
    g_[12] = DPP_I(g_[0], 0x12C); g_[13] = DPP_I(g_[1], 0x12C);     \
    g_[14] = DPP_I(g_[2], 0x12C); g_[15] = DPP_I(g_[3], 0x12C);     \
  } while (0)

// lane^16 / lane^32 exchange on the VALU pipe. After duplicating v into two
// regs and swapping complementary 16/32-lane blocks between them, the partner
// value lands in exactly one of the two regs per lane; 'sel' (calibrated once
// with lane_id, hoisted into an SGPR mask) picks it. s_nop covers the
// VALU-write -> permlane-read wait states (inline asm bypasses the compiler's
// hazard recognizer).
__device__ __forceinline__ float sw16(float v, bool sel) {
  int x = __float_as_int(v), y = x;
  asm volatile("s_nop 1\n\tv_permlane16_swap_b32 %0, %1" : "+v"(x), "+v"(y));
  return sel ? __int_as_float(x) : __int_as_float(y);
}
__device__ __forceinline__ float sw32(float v, bool sel) {
  int x = __float_as_int(v), y = x;
  asm volatile("s_nop 1\n\tv_permlane32_swap_b32 %0, %1" : "+v"(x), "+v"(y));
  return sel ? __int_as_float(x) : __int_as_float(y);
}

// ---------------------------------------------------------------------------
// Kernel 2: sequential scan, one wave per batch row. The h-broadcast for
// h @ Whh is done entirely in-register (DPP row gather + permlane combines):
// NO LDS op in the recurrence chain. Per step:
//   16 DPP movs (row all-gather) -> 32 pk_fma (4 column partials) ->
//   2x permlane16_swap + 1x permlane32_swap combine -> exp/rcp tanh.
// Everything on the VALU pipe: step is issue-bound (~180-220 cyc) instead of
// LDS-round-trip-bound (~570 cyc).
// ---------------------------------------------------------------------------
__global__ __launch_bounds__(64)
__attribute__((amdgpu_waves_per_eu(1, 1)))
void scan_kernel(
    const int* __restrict__ tok, const float* __restrict__ P,
    const float* __restrict__ Whh, const float* __restrict__ Wout,
    const float* __restrict__ bout, float* __restrict__ out) {
  const int row  = blockIdx.x;
  const int lane = threadIdx.x;

  // ---- calibration: discover gather permutation + swap register-select ----
  int gcal[16];
  GATHER_ROW(lane, gcal);  // gcal[s] = source lane (== unit index) of slot s

  int x16 = lane, y16 = lane;
  asm volatile("s_nop 1\n\tv_permlane16_swap_b32 %0, %1" : "+v"(x16), "+v"(y16));
  const bool sel16 = (x16 == (lane ^ 16));
  int x32 = lane, y32 = lane;
  asm volatile("s_nop 1\n\tv_permlane32_swap_b32 %0, %1" : "+v"(x32), "+v"(y32));
  const bool sel32 = (x32 == (lane ^ 32));

  // ---- weights: 4 columns (lane, ^16, ^32, ^48) x own-row 16 inputs,
  // permuted to gather order, pre-scaled x2, pinned in VGPRs ----
  const int c0 = lane, c1 = lane ^ 16, c2 = lane ^ 32, c3 = lane ^ 48;
  v2f w0[8], w1[8], w2[8], w3[8];
#pragma unroll
  for (int s = 0; s < 8; ++s) {
    const int i0 = gcal[2 * s] * UNITS, i1 = gcal[2 * s + 1] * UNITS;
    float t00 = 2.f * Whh[i0 + c0], t01 = 2.f * Whh[i1 + c0];
    float t10 = 2.f * Whh[i0 + c1], t11 = 2.f * Whh[i1 + c1];
    float t20 = 2.f * Whh[i0 + c2], t21 = 2.f * Whh[i1 + c2];
    float t30 = 2.f * Whh[i0 + c3], t31 = 2.f * Whh[i1 + c3];
    asm volatile("" : "+v"(t00), "+v"(t01), "+v"(t10), "+v"(t11));
    asm volatile("" : "+v"(t20), "+v"(t21), "+v"(t30), "+v"(t31));
    w0[s].x = t00; w0[s].y = t01;  w1[s].x = t10; w1[s].y = t11;
    w2[s].x = t20; w2[s].y = t21;  w3[s].x = t30; w3[s].y = t31;
  }

  // ---- all 512 tokens of this row, pre-scaled by UNITS (coalesced) ----
  int tokv[SEQ / 64];
  const int* trow = tok + (long)row * SEQ;
#pragma unroll
  for (int c = 0; c < SEQ / 64; ++c) {
    int t = trow[c * 64 + lane] * UNITS;
    asm volatile("" : "+v"(t));
    tokv[c] = t;
  }

  float h = 0.f;

  // distance-2 P prefetch ring: a0 = row(t), a1 = row(t+1); step shrank below
  // the ~200-cyc L2 hit latency so distance-1 would expose it.
  int tka = __builtin_amdgcn_readlane(tokv[0], 0);
  int tkb = __builtin_amdgcn_readlane(tokv[0], 1);
  float a0 = P[(long)tka + lane];
  float a1 = P[(long)tkb + lane];

#pragma unroll
  for (int c = 0; c < SEQ / 64; ++c) {
#pragma unroll 2
    for (int tt = 0; tt < 64; ++tt) {
      float a_cur = a0;
      a0 = a1;
      int tkn = __builtin_amdgcn_readlane(tokv[c], (tt + 2) & 63);
      a1 = P[(long)tkn + lane];  // garbage at tt=62,63; patched after the loop

      // ---- in-register all-gather of h across own 16-lane row ----
      int gi[16];
      GATHER_ROW(__float_as_int(h), gi);

      // ---- 4 column partials, 4 independent 8-deep pk_fma chains;
      // a_cur folded into own-column acc init ----
      v2f acc0, acc1 = {0.f, 0.f}, acc2 = {0.f, 0.f}, acc3 = {0.f, 0.f};
      acc0.x = a_cur; acc0.y = 0.f;
#pragma unroll
      for (int s = 0; s < 8; ++s) {
        v2f gp;
        gp.x = __int_as_float(gi[2 * s]);
        gp.y = __int_as_float(gi[2 * s + 1]);
        acc0 += gp * w0[s];
        acc1 += gp * w1[s];
        acc2 += gp * w2[s];
        acc3 += gp * w3[s];
      }
      float p0 = acc0.x + acc0.y;   // col lane      (incl. a_cur)
      float p1 = acc1.x + acc1.y;   // col lane^16
      float p2 = acc2.x + acc2.y;   // col lane^32
      float p3 = acc3.x + acc3.y;   // col lane^48

      // combine: y[j] = P0(j) + P1(j^16) + P2(j^32) + P3(j^48)
      float s1 = p0 + sw16(p1, sel16);      // half(j) partial for col j
      float s2 = p2 + sw16(p3, sel16);      // half(j) partial for col j^32
      float yv = s1 + sw32(s2, sel32);      // == 2 * preactivation (x2 scale)

      // tanh(s) = 1 - 2/(exp(2s)+1); yv is already 2s
      float e = __expf(yv);
      h = 1.f - 2.f / (e + 1.f);
    }
    if (c + 1 < SEQ / 64) {  // restore ring invariant for next chunk
      int ta = __builtin_amdgcn_readlane(tokv[c + 1], 0);
      int tb = __builtin_amdgcn_readlane(tokv[c + 1], 1);
      a0 = P[(long)ta + lane];
      a1 = P[(long)tb + lane];
    }
  }

  // out[row] = sigmoid(sum_j h[j]*Wout[j] + bout)
  float p = h * Wout[lane];
#pragma unroll
  for (int off = 32; off > 0; off >>= 1) p += __shfl_xor(p, off);
  if (lane == 0) out[row] = 1.f / (1.f + __expf(-(p + bout[0])));
}

extern "C" void kernel_launch(void* const* d_in, const int* in_sizes, int n_in,
                              void* d_out, int out_size, void* d_ws, size_t ws_size,
                              hipStream_t stream) {
  const int*   tok  = (const int*)  d_in[0];  // [BATCH, SEQ] int32
  const float* emb  = (const float*)d_in[1];  // [VOCAB, EMB]
  const float* Wxh  = (const float*)d_in[2];  // [EMB, UNITS]
  const float* Whh  = (const float*)d_in[3];  // [UNITS, UNITS]
  const float* bias = (const float*)d_in[4];  // [UNITS]
  const float* Wout = (const float*)d_in[5];  // [UNITS, 1]
  const float* bout = (const float*)d_in[6];  // [1]
  float* out = (float*)d_out;                 // [BATCH, 1] fp32

  float* P = (float*)d_ws;                    // VOCAB*UNITS fp32 = 256 KB

  proj_kernel<<<VOCAB, 64, 0, stream>>>(emb, Wxh, bias, P);
  scan_kernel<<<BATCH, 64, 0, stream>>>(tok, P, Whh, Wout, bout, out);
}